// Round 2
// baseline (709.320 us; speedup 1.0000x reference)
//
#include <hip/hip_runtime.h>

// Problem constants (from reference): N points, D dims, M centroids.
constexpr int N_ = 65536;
constexpr int D_ = 64;
constexpr int M_ = 4096;
constexpr int CHUNKS = 4;          // split M across blocks for occupancy
constexpr int MC = M_ / CHUNKS;    // centroids per chunk

// Pack (dist,label) so that u64 atomicMin == (min dist, then min label).
// dist >= 0 (squared distance) so float bit pattern is order-preserving.
__device__ inline unsigned long long pack_dl(float d, int m) {
    return ((unsigned long long)__float_as_uint(d) << 32) | (unsigned)m;
}

__global__ __launch_bounds__(256) void pwd_chunk(
        const float* __restrict__ p, const float* __restrict__ pn,
        const float* __restrict__ c, const float* __restrict__ c_sq,
        unsigned long long* __restrict__ ws) {
    const int n = blockIdx.x * 256 + threadIdx.x;
    const int mbase = blockIdx.y * MC;

    // p row -> 64 VGPRs (16 x float4 coalesced loads)
    float pr[D_];
    const float4* p4 = reinterpret_cast<const float4*>(p + (size_t)n * D_);
#pragma unroll
    for (int i = 0; i < D_ / 4; ++i) {
        float4 v = p4[i];
        pr[4 * i + 0] = v.x; pr[4 * i + 1] = v.y;
        pr[4 * i + 2] = v.z; pr[4 * i + 3] = v.w;
    }
    const float pnn = pn[n];

    float bestD = INFINITY;
    int   bestM = mbase;

#pragma unroll 2
    for (int mi = 0; mi < MC; ++mi) {
        const int m = mbase + mi;
        const float* cm = c + (size_t)m * D_;   // wave-uniform -> s_load
        float a0 = 0.f, a1 = 0.f, a2 = 0.f, a3 = 0.f;
#pragma unroll
        for (int k = 0; k < D_; k += 4) {
            a0 = fmaf(pr[k + 0], cm[k + 0], a0);
            a1 = fmaf(pr[k + 1], cm[k + 1], a1);
            a2 = fmaf(pr[k + 2], cm[k + 2], a2);
            a3 = fmaf(pr[k + 3], cm[k + 3], a3);
        }
        const float dot = (a0 + a1) + (a2 + a3);
        const float dist = fmaf(-2.f, dot, pnn + c_sq[m]);
        if (dist < bestD) { bestD = dist; bestM = m; }  // strict < => first index wins
    }
    atomicMin(&ws[n], pack_dl(bestD, bestM));
}

__global__ __launch_bounds__(256) void pwd_finish(
        const unsigned long long* __restrict__ ws, float* __restrict__ out) {
    const int n = blockIdx.x * 256 + threadIdx.x;
    const unsigned long long v = ws[n];
    out[n]      = __uint_as_float((unsigned)(v >> 32));
    out[N_ + n] = (float)(unsigned)(v & 0xffffffffu);
}

// Fallback if ws is too small: full-M per thread, direct store.
__global__ __launch_bounds__(256) void pwd_full(
        const float* __restrict__ p, const float* __restrict__ pn,
        const float* __restrict__ c, const float* __restrict__ c_sq,
        float* __restrict__ out) {
    const int n = blockIdx.x * 256 + threadIdx.x;
    float pr[D_];
    const float4* p4 = reinterpret_cast<const float4*>(p + (size_t)n * D_);
#pragma unroll
    for (int i = 0; i < D_ / 4; ++i) {
        float4 v = p4[i];
        pr[4 * i + 0] = v.x; pr[4 * i + 1] = v.y;
        pr[4 * i + 2] = v.z; pr[4 * i + 3] = v.w;
    }
    const float pnn = pn[n];
    float bestD = INFINITY;
    int   bestM = 0;
#pragma unroll 2
    for (int m = 0; m < M_; ++m) {
        const float* cm = c + (size_t)m * D_;
        float a0 = 0.f, a1 = 0.f, a2 = 0.f, a3 = 0.f;
#pragma unroll
        for (int k = 0; k < D_; k += 4) {
            a0 = fmaf(pr[k + 0], cm[k + 0], a0);
            a1 = fmaf(pr[k + 1], cm[k + 1], a1);
            a2 = fmaf(pr[k + 2], cm[k + 2], a2);
            a3 = fmaf(pr[k + 3], cm[k + 3], a3);
        }
        const float dot = (a0 + a1) + (a2 + a3);
        const float dist = fmaf(-2.f, dot, pnn + c_sq[m]);
        if (dist < bestD) { bestD = dist; bestM = m; }
    }
    out[n]      = bestD;
    out[N_ + n] = (float)bestM;
}

extern "C" void kernel_launch(void* const* d_in, const int* in_sizes, int n_in,
                              void* d_out, int out_size, void* d_ws, size_t ws_size,
                              hipStream_t stream) {
    const float* p    = (const float*)d_in[0];   // [N, D]
    const float* pn   = (const float*)d_in[1];   // [N, 1]
    const float* c    = (const float*)d_in[2];   // [M, D]
    const float* c_sq = (const float*)d_in[3];   // [1, M]
    float* out = (float*)d_out;                  // [N] dists ++ [N] labels

    if (ws_size >= (size_t)N_ * sizeof(unsigned long long)) {
        hipMemsetAsync(d_ws, 0xFF, (size_t)N_ * sizeof(unsigned long long), stream);
        dim3 grid(N_ / 256, CHUNKS);
        pwd_chunk<<<grid, 256, 0, stream>>>(p, pn, c, c_sq,
                                            (unsigned long long*)d_ws);
        pwd_finish<<<N_ / 256, 256, 0, stream>>>((unsigned long long*)d_ws, out);
    } else {
        pwd_full<<<N_ / 256, 256, 0, stream>>>(p, pn, c, c_sq, out);
    }
}